// Round 4
// baseline (1745.490 us; speedup 1.0000x reference)
//
#include <hip/hip_runtime.h>
#include <hip/hip_bf16.h>
#include <math.h>

#define Bq 64
#define Sq 5
#define Hq 50
#define Tq 30
#define Dq 300
#define Fq 400
#define Qq 200
#define G3 1200
#define NCAND (Bq*Sq)
#define NCLK  (Bq*Hq)

typedef __attribute__((ext_vector_type(8))) short bf16x8;
typedef __attribute__((ext_vector_type(8))) _Float16 f16x8;
typedef __attribute__((ext_vector_type(4))) float f32x4;

__device__ __forceinline__ float sigmoidf_(float x){ return 1.f/(1.f+expf(-x)); }
__device__ __forceinline__ unsigned short f2bf(float x){
  __hip_bfloat16 b = __float2bfloat16(x);
  return *reinterpret_cast<unsigned short*>(&b);
}
__device__ __forceinline__ float bf2f(unsigned short u){
  __hip_bfloat16 b; *reinterpret_cast<unsigned short*>(&b) = u;
  return __bfloat162float(b);
}

// ---------------- weight prep (one-time per call, tiny) ----------------
__global__ __launch_bounds__(256) void conv_prep_kernel(
    const float* __restrict__ c_cw, const float* __restrict__ u_cw,
    __hip_bfloat16* __restrict__ out)
{
  const int PER = 30*16384;
  int idx = blockIdx.x*256 + threadIdx.x;
  if (idx >= 2*PER) return;
  int enc = idx / PER, rem = idx - enc*PER;
  int chunk = rem >> 14;
  int e = rem & 16383;
  int sub = e >> 12;
  int col = (e >> 3) & 511;
  int j = e & 7;
  int w = chunk / 10, s = chunk - w*10;
  int d = s*32 + sub*8 + j;
  const float* cw = enc ? u_cw : c_cw;
  float v = (d < Dq && col < Fq) ? cw[(w*Dq + d)*Fq + col] : 0.f;
  out[idx] = __float2bfloat16(v);
}

__global__ __launch_bounds__(256) void att_prep_kernel(
    const float* __restrict__ c_aW, const float* __restrict__ u_aW,
    __hip_bfloat16* __restrict__ out)
{
  const int PER = 13*8192;
  int idx = blockIdx.x*256 + threadIdx.x;
  if (idx >= 2*PER) return;
  int enc = idx / PER, rem = idx - enc*PER;
  int chunk = rem >> 13;
  int e = rem & 8191;
  int sub = e >> 11;
  int col = (e >> 3) & 255;
  int j = e & 7;
  int k = chunk*32 + sub*8 + j;
  const float* aW = enc ? u_aW : c_aW;
  float v = (k < Fq && col < Qq) ? aW[k*Qq + col] : 0.f;
  out[idx] = __float2bfloat16(v);
}

// whh -> fp16 MFMA-B-fragment order: [gc 16][kt 13][l4 4][n 80][j 8]
// gate g = gc*75+n (n<75 valid), k = kt*32+l4*8+j (k<400 valid)
__global__ __launch_bounds__(256) void whh_f16_prep_kernel(
    const float* __restrict__ whh, _Float16* __restrict__ out)
{
  const int TOT = 16*13*4*80*8;   // 532480
  int idx = blockIdx.x*256 + threadIdx.x;
  if (idx >= TOT) return;
  int j  = idx & 7;
  int n  = (idx >> 3) % 80;
  int q  = (idx >> 3) / 80;       // ((gc*13+kt)*4 + l4)
  int l4 = q & 3;
  int kt = (q >> 2) % 13;
  int gc = (q >> 2) / 13;
  int g = gc*75 + n;
  int k = kt*32 + l4*8 + j;
  float v = (n < 75 && k < Fq) ? whh[(size_t)g*Fq + k] : 0.f;
  out[idx] = (_Float16)v;
}

// ---------------- fused encoder (unchanged from round 3) ----------------
#define XROWS 137
#define XBYTES (40*XROWS*16)
#define BBUF0 XBYTES
#define BCHUNK 32768
#define BBUF1 (BBUF0 + BCHUNK)
#define ABUF0 (52*128*16)
#define ACHUNK 16384
#define ABUF1 (ABUF0 + ACHUNK)
#define SCRATCH (BBUF1 + BCHUNK)
#define SMEM_BYTES (SCRATCH + 1088)

__global__ __launch_bounds__(512, 2) void encode_mfma_kernel(
    const float* __restrict__ cand_emb, const float* __restrict__ clk_emb,
    const __hip_bfloat16* __restrict__ convprep,
    const __hip_bfloat16* __restrict__ attprep,
    const float* __restrict__ c_cb, const float* __restrict__ c_ab, const float* __restrict__ c_aq,
    const float* __restrict__ c_lg, const float* __restrict__ c_lb,
    const float* __restrict__ u_cb, const float* __restrict__ u_ab, const float* __restrict__ u_aq,
    const float* __restrict__ u_lg, const float* __restrict__ u_lb,
    float* __restrict__ cand_rep, float* __restrict__ clicked_rep)
{
  __shared__ __align__(16) unsigned char smem[SMEM_BYTES];
  float* sscore = (float*)(smem + SCRATCH);
  float* sa_    = sscore + 128;
  float* red_   = sa_ + 128;

  const int b = blockIdx.x, tid = threadIdx.x;
  const bool cand = b < (NCAND/4);
  const int n0 = cand ? b*4 : (b - NCAND/4)*4;
  const float* x = (cand ? cand_emb : clk_emb) + (size_t)n0*Tq*Dq;
  const __hip_bfloat16* Wp = convprep + (cand ? 0 : 30*16384);
  const __hip_bfloat16* Ap = attprep  + (cand ? 0 : 13*8192);
  const float* cb = cand ? c_cb : u_cb;
  const float* ab = cand ? c_ab : u_ab;
  const float* aq = cand ? c_aq : u_aq;
  const float* lg = cand ? c_lg : u_lg;
  const float* lb = cand ? c_lb : u_lb;

  const int lane = tid & 63, wid = tid >> 6;
  const int mh = wid >> 2, nq = wid & 3;
  const int l15 = lane & 15, l4 = lane >> 4;

  if (tid < 128) sscore[tid] = 0.f;

  for (int i = tid; i < 40*XROWS; i += 512) {
    int c = i % 40, r = i / 40;
    float4 va = {0.f,0.f,0.f,0.f}, vb = {0.f,0.f,0.f,0.f};
    if (r < 128) {
      int lr = r & 31, tt = r >> 5;
      if (lr >= 1 && lr <= 30) {
        int t = lr - 1, d0 = c*8;
        if (d0 < Dq) {
          const float* src = x + (size_t)tt*Tq*Dq + t*Dq + d0;
          va = *(const float4*)src;
          if (d0 + 4 < Dq) vb = *(const float4*)(src + 4);
        }
      }
    }
    union { bf16x8 v; unsigned short u[8]; } pk;
    pk.u[0]=f2bf(va.x); pk.u[1]=f2bf(va.y); pk.u[2]=f2bf(va.z); pk.u[3]=f2bf(va.w);
    pk.u[4]=f2bf(vb.x); pk.u[5]=f2bf(vb.y); pk.u[6]=f2bf(vb.z); pk.u[7]=f2bf(vb.w);
    *(bf16x8*)(smem + (size_t)(c*XROWS + r)*16) = pk.v;
  }

  f32x4 acc[4][7];
  float cbv[7];
  #pragma unroll
  for (int nf = 0; nf < 7; ++nf) {
    int colg = (nq*7 + nf)*16 + l15;
    cbv[nf] = (colg < Fq) ? cb[colg] : 0.f;
  }
  #pragma unroll
  for (int mf = 0; mf < 4; ++mf)
    #pragma unroll
    for (int nf = 0; nf < 7; ++nf)
      acc[mf][nf] = (f32x4){cbv[nf], cbv[nf], cbv[nf], cbv[nf]};

  {
    const __hip_bfloat16* src = Wp;
    #pragma unroll
    for (int k = 0; k < 4; ++k) {
      uint4 v = *(const uint4*)(src + k*4096 + tid*8);
      *(uint4*)(smem + BBUF0 + k*8192 + tid*16) = v;
    }
  }
  __syncthreads();

  for (int step = 0; step < 30; ++step) {
    const int w = step / 10, s = step - w*10;
    const int cbuf = step & 1;
    uint4 nx0, nx1, nx2, nx3;
    const bool have = (step < 29);
    if (have) {
      const __hip_bfloat16* src = Wp + (size_t)(step+1)*16384;
      nx0 = *(const uint4*)(src + 0*4096 + tid*8);
      nx1 = *(const uint4*)(src + 1*4096 + tid*8);
      nx2 = *(const uint4*)(src + 2*4096 + tid*8);
      nx3 = *(const uint4*)(src + 3*4096 + tid*8);
    }
    bf16x8 a[4];
    #pragma unroll
    for (int mf = 0; mf < 4; ++mf) {
      int arow = mh*64 + mf*16 + l15 + w;
      int c = s*4 + l4;
      a[mf] = *(const bf16x8*)(smem + (size_t)(c*XROWS + arow)*16);
    }
    bf16x8 bb[7];
    const unsigned char* bbase = smem + (cbuf ? BBUF1 : BBUF0);
    #pragma unroll
    for (int nf = 0; nf < 7; ++nf) {
      int col = (nq*7 + nf)*16 + l15;
      bb[nf] = *(const bf16x8*)(bbase + (size_t)(l4*512 + col)*16);
    }
    #pragma unroll
    for (int mf = 0; mf < 4; ++mf)
      #pragma unroll
      for (int nf = 0; nf < 7; ++nf)
        acc[mf][nf] = __builtin_amdgcn_mfma_f32_16x16x32_bf16(a[mf], bb[nf], acc[mf][nf], 0, 0, 0);
    if (have) {
      unsigned char* obase = smem + (cbuf ? BBUF0 : BBUF1);
      *(uint4*)(obase + 0*8192 + tid*16) = nx0;
      *(uint4*)(obase + 1*8192 + tid*16) = nx1;
      *(uint4*)(obase + 2*8192 + tid*16) = nx2;
      *(uint4*)(obase + 3*8192 + tid*16) = nx3;
    }
    __syncthreads();
  }

  {
    #pragma unroll
    for (int k = 0; k < 2; ++k) {
      uint4 v = *(const uint4*)(Ap + k*4096 + tid*8);
      *(uint4*)(smem + ABUF0 + k*8192 + tid*16) = v;
    }
  }
  #pragma unroll
  for (int mf = 0; mf < 4; ++mf) {
    #pragma unroll
    for (int nf = 0; nf < 7; ++nf) {
      int colg = (nq*7 + nf)*16 + l15;
      if (colg < 416) {
        #pragma unroll
        for (int i = 0; i < 4; ++i) {
          int row = mh*64 + mf*16 + l4*4 + i;
          float v = fmaxf(acc[mf][nf][i], 0.f);
          *(unsigned short*)(smem + (size_t)((colg >> 3)*128 + row)*16 + (colg & 7)*2) = f2bf(v);
        }
      }
    }
  }
  __syncthreads();

  f32x4 acc2[4][4];
  #pragma unroll
  for (int mf = 0; mf < 4; ++mf)
    #pragma unroll
    for (int nn = 0; nn < 4; ++nn)
      acc2[mf][nn] = (f32x4){0.f,0.f,0.f,0.f};
  const int nf0  = (nq == 0) ? 0 : (1 + 3*nq);
  const int ncnt = (nq == 0) ? 4 : 3;

  for (int s2 = 0; s2 < 13; ++s2) {
    const int cbuf = s2 & 1;
    uint4 nx0, nx1;
    const bool have = (s2 < 12);
    if (have) {
      const __hip_bfloat16* src = Ap + (size_t)(s2+1)*8192;
      nx0 = *(const uint4*)(src + 0*4096 + tid*8);
      nx1 = *(const uint4*)(src + 1*4096 + tid*8);
    }
    bf16x8 a2[4];
    #pragma unroll
    for (int mf = 0; mf < 4; ++mf) {
      int row = mh*64 + mf*16 + l15;
      int fchunk = s2*4 + l4;
      a2[mf] = *(const bf16x8*)(smem + (size_t)(fchunk*128 + row)*16);
    }
    bf16x8 b2[4];
    const unsigned char* bbase = smem + (cbuf ? ABUF1 : ABUF0);
    #pragma unroll
    for (int nn = 0; nn < 4; ++nn) {
      if (nn < ncnt) {
        int col = (nf0 + nn)*16 + l15;
        b2[nn] = *(const bf16x8*)(bbase + (size_t)(l4*256 + col)*16);
      }
    }
    #pragma unroll
    for (int mf = 0; mf < 4; ++mf)
      #pragma unroll
      for (int nn = 0; nn < 4; ++nn)
        if (nn < ncnt)
          acc2[mf][nn] = __builtin_amdgcn_mfma_f32_16x16x32_bf16(a2[mf], b2[nn], acc2[mf][nn], 0, 0, 0);
    if (have) {
      unsigned char* obase = smem + (cbuf ? ABUF0 : ABUF1);
      *(uint4*)(obase + 0*8192 + tid*16) = nx0;
      *(uint4*)(obase + 1*8192 + tid*16) = nx1;
    }
    __syncthreads();
  }

  {
    float abv[4], aqv[4];
    #pragma unroll
    for (int nn = 0; nn < 4; ++nn) {
      int col = (nf0 + nn)*16 + l15;
      bool ok = (nn < ncnt) && (col < Qq);
      abv[nn] = ok ? ab[col] : 0.f;
      aqv[nn] = ok ? aq[col] : 0.f;
    }
    #pragma unroll
    for (int mf = 0; mf < 4; ++mf) {
      #pragma unroll
      for (int i = 0; i < 4; ++i) {
        float p = 0.f;
        #pragma unroll
        for (int nn = 0; nn < 4; ++nn)
          if (nn < ncnt)
            p += tanhf(acc2[mf][nn][i] + abv[nn]) * aqv[nn];
        p += __shfl_xor(p, 1); p += __shfl_xor(p, 2);
        p += __shfl_xor(p, 4); p += __shfl_xor(p, 8);
        if (l15 == 0) atomicAdd(&sscore[mh*64 + mf*16 + l4*4 + i], p);
      }
    }
  }
  __syncthreads();

  if (tid < 4) {
    float mx = -1e30f;
    for (int t = 0; t < Tq; ++t) mx = fmaxf(mx, sscore[tid*32 + t]);
    float sum = 0.f;
    for (int t = 0; t < Tq; ++t) { float e = expf(sscore[tid*32 + t] - mx); sa_[tid*32 + t] = e; sum += e; }
    float inv = 1.f / sum;
    for (int t = 0; t < Tq; ++t) sa_[tid*32 + t] *= inv;
    sa_[tid*32 + 30] = 0.f; sa_[tid*32 + 31] = 0.f;
  }
  __syncthreads();

  {
    const int tt = tid >> 7, fb = tid & 127;
    float rv[4];
    float ls = 0.f, lsq = 0.f;
    #pragma unroll
    for (int q = 0; q < 4; ++q) {
      int f = fb + q*128;
      rv[q] = 0.f;
      if (f < Fq) {
        float r = 0.f;
        const unsigned char* hb = smem + (size_t)(f >> 3)*128*16 + (f & 7)*2;
        for (int t = 0; t < Tq; ++t)
          r += sa_[tt*32 + t] * bf2f(*(const unsigned short*)(hb + (size_t)(tt*32 + t)*16));
        rv[q] = r; ls += r; lsq += r*r;
      }
    }
    #pragma unroll
    for (int off = 32; off >= 1; off >>= 1) { ls += __shfl_xor(ls, off); lsq += __shfl_xor(lsq, off); }
    if (lane == 0) { red_[wid] = ls; red_[8 + wid] = lsq; }
    __syncthreads();
    float tot  = red_[2*tt] + red_[2*tt + 1];
    float totq = red_[8 + 2*tt] + red_[8 + 2*tt + 1];
    float mu = tot * (1.f/Fq);
    float var = totq * (1.f/Fq) - mu*mu;
    float rs = rsqrtf(var + 1e-5f);
    float* dst = (cand ? cand_rep : clicked_rep) + (size_t)(n0 + tt)*Fq;
    #pragma unroll
    for (int q = 0; q < 4; ++q) {
      int f = fb + q*128;
      if (f < Fq) dst[f] = (rv[q] - mu)*rs*lg[f] + lb[f];
    }
  }
}

// ---------------- GI = clicked_rep @ wih^T + bih ----------------
__global__ __launch_bounds__(256) void gi_kernel(
    const float* __restrict__ rep, const float* __restrict__ wih, const float* __restrict__ bih,
    float* __restrict__ gi)
{
  __shared__ __align__(16) float sA[64*80];
  const int tid = threadIdx.x;
  const int rt = blockIdx.x;
  const int g  = blockIdx.y*256 + tid;
  const bool gok = g < G3;
  const float* wr = wih + (size_t)(gok ? g : 0) * Fq;
  float acc[64];
  #pragma unroll
  for (int r = 0; r < 64; ++r) acc[r] = 0.f;
  for (int kt = 0; kt < Fq; kt += 80) {
    __syncthreads();
    for (int i = tid; i < 64*80; i += 256) {
      int r = i / 80, c = i - r*80;
      sA[i] = rep[(size_t)(rt*64 + r)*Fq + kt + c];
    }
    __syncthreads();
    #pragma unroll 2
    for (int k = 0; k < 80; k += 4) {
      float w0 = wr[kt+k], w1 = wr[kt+k+1], w2 = wr[kt+k+2], w3 = wr[kt+k+3];
      #pragma unroll
      for (int r = 0; r < 64; ++r) {
        float4 a4 = *(const float4*)(sA + r*80 + k);
        acc[r] = fmaf(a4.x,w0,fmaf(a4.y,w1,fmaf(a4.z,w2,fmaf(a4.w,w3,acc[r]))));
      }
    }
  }
  if (gok) {
    float bv = bih[g];
    #pragma unroll 1
    for (int r = 0; r < 64; ++r) gi[(size_t)(rt*64+r)*G3 + g] = acc[r] + bv;
  }
}

// ---------------- GRU: 4 groups x 16 rows, 16 gate-chunk blocks/group ----------------
// Weights live in VGPRs (13 B-frags/wave, loaded once). Per step: MFMA gates ->
// global (double-buffered) -> release counter -> acquire spin -> redundant local
// h-update per block (no second sync). Race-free via buffer parity + counter lag.
#define HPAD 420

__global__ __launch_bounds__(512) void gru_mfma_kernel(
    const float* __restrict__ gi, const _Float16* __restrict__ whh_f16,
    const float* __restrict__ bhh, const int* __restrict__ lens,
    float* __restrict__ gates, int* __restrict__ cnt, float* __restrict__ user_rep)
{
  __shared__ __align__(16) float h_f32[16*HPAD];
  __shared__ int slen[16];
  const int bid = blockIdx.x;
  const int group = bid >> 4, gc = bid & 15;
  const int tid = threadIdx.x;
  const int lane = tid & 63, wv = tid >> 6;
  const int l15 = lane & 15, l4 = lane >> 4;

  if (tid < 16) slen[tid] = lens[group*16 + tid];
  for (int i = tid; i < 16*HPAD; i += 512) h_f32[i] = 0.f;

  // B fragments: wave wv (<5) owns gate cols n0=wv*16 .. +15 of chunk gc
  f16x8 bfrag[13];
  if (wv < 5) {
    const _Float16* base = whh_f16 + (size_t)gc*(13*4*640);
    #pragma unroll
    for (int kt = 0; kt < 13; ++kt)
      bfrag[kt] = *(const f16x8*)(base + (kt*4 + l4)*640 + (wv*16 + l15)*8);
  }
  __syncthreads();

  int Lmax = 1;
  #pragma unroll
  for (int i = 0; i < 16; ++i) Lmax = max(Lmax, slen[i]);

  int* mycnt = cnt + group;
  float* gbuf[2] = { gates + (size_t)group*1200*16,
                     gates + (size_t)(4 + group)*1200*16 };

  for (int t = 0; t < Lmax; ++t) {
    float* gb_w = gbuf[t & 1];
    if (wv < 5) {
      f32x4 acc = (f32x4){0.f,0.f,0.f,0.f};
      #pragma unroll
      for (int kt = 0; kt < 13; ++kt) {
        const float* hp = h_f32 + l15*HPAD + kt*32 + l4*8;
        float4 ha = *(const float4*)hp;
        float4 hb = *(const float4*)(hp + 4);
        union { f16x8 v; _Float16 e[8]; } af;
        af.e[0]=(_Float16)ha.x; af.e[1]=(_Float16)ha.y; af.e[2]=(_Float16)ha.z; af.e[3]=(_Float16)ha.w;
        af.e[4]=(_Float16)hb.x; af.e[5]=(_Float16)hb.y; af.e[6]=(_Float16)hb.z; af.e[7]=(_Float16)hb.w;
        acc = __builtin_amdgcn_mfma_f32_16x16x32_f16(af.v, bfrag[kt], acc, 0, 0, 0);
      }
      int n = wv*16 + l15;
      if (n < 75) {
        int g = gc*75 + n;
        *(float4*)(gb_w + (size_t)g*16 + l4*4) = (float4){acc[0], acc[1], acc[2], acc[3]};
      }
    }
    __threadfence();      // agent-scope: push gate stores to coherence point
    __syncthreads();
    if (tid == 0)
      __hip_atomic_fetch_add(mycnt, 1, __ATOMIC_RELEASE, __HIP_MEMORY_SCOPE_AGENT);
    const int target = 16*(t+1);
    while (__hip_atomic_load(mycnt, __ATOMIC_ACQUIRE, __HIP_MEMORY_SCOPE_AGENT) < target)
      __builtin_amdgcn_s_sleep(2);

    // redundant h-update for all 16 rows (block-local h copy)
    const float* gb_r = gbuf[t & 1];
    for (int task = tid; task < 16*Fq; task += 512) {
      int r = task & 15, j = task >> 4;
      if (t < slen[r]) {
        int row = group*16 + r;
        float ghr = gb_r[(size_t)j*16 + r]        + bhh[j];
        float ghz = gb_r[(size_t)(400+j)*16 + r]  + bhh[400 + j];
        float ghn = gb_r[(size_t)(800+j)*16 + r]  + bhh[800 + j];
        const float* gib = gi + ((size_t)row*Hq + t)*G3;
        float rg = sigmoidf_(gib[j] + ghr);
        float zg = sigmoidf_(gib[400 + j] + ghz);
        float ng = tanhf   (gib[800 + j] + rg*ghn);
        h_f32[r*HPAD + j] = (1.f - zg)*ng + zg*h_f32[r*HPAD + j];
      }
    }
    __syncthreads();
  }

  if (gc == 0) {
    for (int i = tid; i < 16*Fq; i += 512) {
      int r = i / Fq, j = i - r*Fq;
      user_rep[(size_t)(group*16 + r)*Fq + j] = h_f32[r*HPAD + j];
    }
  }
}

__global__ __launch_bounds__(64) void score_kernel(
    const float* __restrict__ cand_rep, const float* __restrict__ user_rep,
    float* __restrict__ out)
{
  const int i = blockIdx.x;
  const int b = i / Sq;
  const int lane = threadIdx.x;
  float acc = 0.f;
  for (int f = lane; f < Fq; f += 64) acc = fmaf(cand_rep[(size_t)i*Fq+f], user_rep[(size_t)b*Fq+f], acc);
  #pragma unroll
  for (int off = 32; off >= 1; off >>= 1) acc += __shfl_xor(acc, off);
  if (lane == 0) out[i] = acc;
}

extern "C" void kernel_launch(void* const* d_in, const int* in_sizes, int n_in,
                              void* d_out, int out_size, void* d_ws, size_t ws_size,
                              hipStream_t stream)
{
  const float* cand_emb = (const float*)d_in[0];
  const float* clk_emb  = (const float*)d_in[1];
  const int*   lens     = (const int*)  d_in[2];
  const float* c_cw = (const float*)d_in[3];
  const float* c_cb = (const float*)d_in[4];
  const float* c_aW = (const float*)d_in[5];
  const float* c_ab = (const float*)d_in[6];
  const float* c_aq = (const float*)d_in[7];
  const float* c_lg = (const float*)d_in[8];
  const float* c_lb = (const float*)d_in[9];
  const float* u_cw = (const float*)d_in[10];
  const float* u_cb = (const float*)d_in[11];
  const float* u_aW = (const float*)d_in[12];
  const float* u_ab = (const float*)d_in[13];
  const float* u_aq = (const float*)d_in[14];
  const float* u_lg = (const float*)d_in[15];
  const float* u_lb = (const float*)d_in[16];
  const float* wih  = (const float*)d_in[17];
  const float* whh  = (const float*)d_in[18];
  const float* bih  = (const float*)d_in[19];
  const float* bhh  = (const float*)d_in[20];

  float* ws = (float*)d_ws;
  float* cand_rep    = ws;                        // 128,000 f
  float* clicked_rep = cand_rep + NCAND*Fq;       // +1,280,000 -> 1,408,000
  float* gi          = clicked_rep + NCLK*Fq;     // +3,840,000 -> 5,248,000
  float* user_rep    = gi + (size_t)NCLK*G3;      // +25,600    -> 5,273,600
  _Float16* whh_f16  = (_Float16*)(user_rep + Bq*Fq);   // 532,480 halves = 266,240 f
  float* gates       = (float*)(whh_f16 + 532480);      // 153,600 f
  int*   cnt         = (int*)(gates + 2*4*1200*16);     // 4 ints
  // bf16 encoder-prep buffers overlay gi (dead until gi_kernel)
  __hip_bfloat16* convprep = (__hip_bfloat16*)gi;
  __hip_bfloat16* attprep  = (__hip_bfloat16*)(gi + 491520);

  hipMemsetAsync(cnt, 0, 4*sizeof(int), stream);

  conv_prep_kernel<<<(2*30*16384 + 255)/256, 256, 0, stream>>>(c_cw, u_cw, convprep);
  att_prep_kernel<<<(2*13*8192 + 255)/256, 256, 0, stream>>>(c_aW, u_aW, attprep);
  whh_f16_prep_kernel<<<(16*13*4*80*8 + 255)/256, 256, 0, stream>>>(whh, whh_f16);

  encode_mfma_kernel<<<(NCAND + NCLK)/4, 512, 0, stream>>>(
      cand_emb, clk_emb, convprep, attprep,
      c_cb, c_ab, c_aq, c_lg, c_lb,
      u_cb, u_ab, u_aq, u_lg, u_lb,
      cand_rep, clicked_rep);

  gi_kernel<<<dim3(NCLK/64, 5), 256, 0, stream>>>(clicked_rep, wih, bih, gi);

  gru_mfma_kernel<<<64, 512, 0, stream>>>(gi, whh_f16, bhh, lens, gates, cnt, user_rep);

  score_kernel<<<NCAND, 64, 0, stream>>>(cand_rep, user_rep, (float*)d_out);
}

// Round 5
// 934.293 us; speedup vs baseline: 1.8682x; 1.8682x over previous
//
#include <hip/hip_runtime.h>
#include <hip/hip_bf16.h>
#include <math.h>

#define Bq 64
#define Sq 5
#define Hq 50
#define Tq 30
#define Dq 300
#define Fq 400
#define Qq 200
#define G3 1200
#define NCAND (Bq*Sq)
#define NCLK  (Bq*Hq)

typedef __attribute__((ext_vector_type(8))) short bf16x8;
typedef __attribute__((ext_vector_type(2))) _Float16 h2;
typedef __attribute__((ext_vector_type(4))) float f32x4;

__device__ __forceinline__ float sigmoidf_(float x){ return 1.f/(1.f+expf(-x)); }
__device__ __forceinline__ unsigned short f2bf(float x){
  __hip_bfloat16 b = __float2bfloat16(x);
  return *reinterpret_cast<unsigned short*>(&b);
}
__device__ __forceinline__ float bf2f(unsigned short u){
  __hip_bfloat16 b; *reinterpret_cast<unsigned short*>(&b) = u;
  return __bfloat162float(b);
}
// 8-element f16 dot with fp32 accumulate (4x v_dot2_f32_f16)
__device__ __forceinline__ float dot8_(uint4 h, uint4 w, float acc){
  union { unsigned u; h2 v; } a, b;
  a.u = h.x; b.u = w.x; acc = __builtin_amdgcn_fdot2(a.v, b.v, acc, false);
  a.u = h.y; b.u = w.y; acc = __builtin_amdgcn_fdot2(a.v, b.v, acc, false);
  a.u = h.z; b.u = w.z; acc = __builtin_amdgcn_fdot2(a.v, b.v, acc, false);
  a.u = h.w; b.u = w.w; acc = __builtin_amdgcn_fdot2(a.v, b.v, acc, false);
  return acc;
}

// ---------------- weight prep (one-time per call, tiny) ----------------
__global__ __launch_bounds__(256) void conv_prep_kernel(
    const float* __restrict__ c_cw, const float* __restrict__ u_cw,
    __hip_bfloat16* __restrict__ out)
{
  const int PER = 30*16384;
  int idx = blockIdx.x*256 + threadIdx.x;
  if (idx >= 2*PER) return;
  int enc = idx / PER, rem = idx - enc*PER;
  int chunk = rem >> 14;
  int e = rem & 16383;
  int sub = e >> 12;
  int col = (e >> 3) & 511;
  int j = e & 7;
  int w = chunk / 10, s = chunk - w*10;
  int d = s*32 + sub*8 + j;
  const float* cw = enc ? u_cw : c_cw;
  float v = (d < Dq && col < Fq) ? cw[(w*Dq + d)*Fq + col] : 0.f;
  out[idx] = __float2bfloat16(v);
}

__global__ __launch_bounds__(256) void att_prep_kernel(
    const float* __restrict__ c_aW, const float* __restrict__ u_aW,
    __hip_bfloat16* __restrict__ out)
{
  const int PER = 13*8192;
  int idx = blockIdx.x*256 + threadIdx.x;
  if (idx >= 2*PER) return;
  int enc = idx / PER, rem = idx - enc*PER;
  int chunk = rem >> 13;
  int e = rem & 8191;
  int sub = e >> 11;
  int col = (e >> 3) & 255;
  int j = e & 7;
  int k = chunk*32 + sub*8 + j;
  const float* aW = enc ? u_aW : c_aW;
  float v = (k < Fq && col < Qq) ? aW[k*Qq + col] : 0.f;
  out[idx] = __float2bfloat16(v);
}

// whh [1200,400] f32 -> f16 layout [k8 50][g 1200][8]: coalesced uint4 per (k8,g)
__global__ __launch_bounds__(256) void whh_h8_prep_kernel(
    const float* __restrict__ whh, _Float16* __restrict__ out)
{
  const int TOT = 50*G3*8;   // 480000
  int idx = blockIdx.x*256 + threadIdx.x;
  if (idx >= TOT) return;
  int j  = idx & 7;
  int g  = (idx >> 3) % G3;
  int k8 = (idx >> 3) / G3;
  out[idx] = (_Float16)whh[(size_t)g*Fq + k8*8 + j];
}

// ---------------- fused encoder (unchanged from round 3) ----------------
#define XROWS 137
#define XBYTES (40*XROWS*16)
#define BBUF0 XBYTES
#define BCHUNK 32768
#define BBUF1 (BBUF0 + BCHUNK)
#define ABUF0 (52*128*16)
#define ACHUNK 16384
#define ABUF1 (ABUF0 + ACHUNK)
#define SCRATCH (BBUF1 + BCHUNK)
#define SMEM_BYTES (SCRATCH + 1088)

__global__ __launch_bounds__(512, 2) void encode_mfma_kernel(
    const float* __restrict__ cand_emb, const float* __restrict__ clk_emb,
    const __hip_bfloat16* __restrict__ convprep,
    const __hip_bfloat16* __restrict__ attprep,
    const float* __restrict__ c_cb, const float* __restrict__ c_ab, const float* __restrict__ c_aq,
    const float* __restrict__ c_lg, const float* __restrict__ c_lb,
    const float* __restrict__ u_cb, const float* __restrict__ u_ab, const float* __restrict__ u_aq,
    const float* __restrict__ u_lg, const float* __restrict__ u_lb,
    float* __restrict__ cand_rep, float* __restrict__ clicked_rep)
{
  __shared__ __align__(16) unsigned char smem[SMEM_BYTES];
  float* sscore = (float*)(smem + SCRATCH);
  float* sa_    = sscore + 128;
  float* red_   = sa_ + 128;

  const int b = blockIdx.x, tid = threadIdx.x;
  const bool cand = b < (NCAND/4);
  const int n0 = cand ? b*4 : (b - NCAND/4)*4;
  const float* x = (cand ? cand_emb : clk_emb) + (size_t)n0*Tq*Dq;
  const __hip_bfloat16* Wp = convprep + (cand ? 0 : 30*16384);
  const __hip_bfloat16* Ap = attprep  + (cand ? 0 : 13*8192);
  const float* cb = cand ? c_cb : u_cb;
  const float* ab = cand ? c_ab : u_ab;
  const float* aq = cand ? c_aq : u_aq;
  const float* lg = cand ? c_lg : u_lg;
  const float* lb = cand ? c_lb : u_lb;

  const int lane = tid & 63, wid = tid >> 6;
  const int mh = wid >> 2, nq = wid & 3;
  const int l15 = lane & 15, l4 = lane >> 4;

  if (tid < 128) sscore[tid] = 0.f;

  for (int i = tid; i < 40*XROWS; i += 512) {
    int c = i % 40, r = i / 40;
    float4 va = {0.f,0.f,0.f,0.f}, vb = {0.f,0.f,0.f,0.f};
    if (r < 128) {
      int lr = r & 31, tt = r >> 5;
      if (lr >= 1 && lr <= 30) {
        int t = lr - 1, d0 = c*8;
        if (d0 < Dq) {
          const float* src = x + (size_t)tt*Tq*Dq + t*Dq + d0;
          va = *(const float4*)src;
          if (d0 + 4 < Dq) vb = *(const float4*)(src + 4);
        }
      }
    }
    union { bf16x8 v; unsigned short u[8]; } pk;
    pk.u[0]=f2bf(va.x); pk.u[1]=f2bf(va.y); pk.u[2]=f2bf(va.z); pk.u[3]=f2bf(va.w);
    pk.u[4]=f2bf(vb.x); pk.u[5]=f2bf(vb.y); pk.u[6]=f2bf(vb.z); pk.u[7]=f2bf(vb.w);
    *(bf16x8*)(smem + (size_t)(c*XROWS + r)*16) = pk.v;
  }

  f32x4 acc[4][7];
  float cbv[7];
  #pragma unroll
  for (int nf = 0; nf < 7; ++nf) {
    int colg = (nq*7 + nf)*16 + l15;
    cbv[nf] = (colg < Fq) ? cb[colg] : 0.f;
  }
  #pragma unroll
  for (int mf = 0; mf < 4; ++mf)
    #pragma unroll
    for (int nf = 0; nf < 7; ++nf)
      acc[mf][nf] = (f32x4){cbv[nf], cbv[nf], cbv[nf], cbv[nf]};

  {
    const __hip_bfloat16* src = Wp;
    #pragma unroll
    for (int k = 0; k < 4; ++k) {
      uint4 v = *(const uint4*)(src + k*4096 + tid*8);
      *(uint4*)(smem + BBUF0 + k*8192 + tid*16) = v;
    }
  }
  __syncthreads();

  for (int step = 0; step < 30; ++step) {
    const int w = step / 10, s = step - w*10;
    const int cbuf = step & 1;
    uint4 nx0, nx1, nx2, nx3;
    const bool have = (step < 29);
    if (have) {
      const __hip_bfloat16* src = Wp + (size_t)(step+1)*16384;
      nx0 = *(const uint4*)(src + 0*4096 + tid*8);
      nx1 = *(const uint4*)(src + 1*4096 + tid*8);
      nx2 = *(const uint4*)(src + 2*4096 + tid*8);
      nx3 = *(const uint4*)(src + 3*4096 + tid*8);
    }
    bf16x8 a[4];
    #pragma unroll
    for (int mf = 0; mf < 4; ++mf) {
      int arow = mh*64 + mf*16 + l15 + w;
      int c = s*4 + l4;
      a[mf] = *(const bf16x8*)(smem + (size_t)(c*XROWS + arow)*16);
    }
    bf16x8 bb[7];
    const unsigned char* bbase = smem + (cbuf ? BBUF1 : BBUF0);
    #pragma unroll
    for (int nf = 0; nf < 7; ++nf) {
      int col = (nq*7 + nf)*16 + l15;
      bb[nf] = *(const bf16x8*)(bbase + (size_t)(l4*512 + col)*16);
    }
    #pragma unroll
    for (int mf = 0; mf < 4; ++mf)
      #pragma unroll
      for (int nf = 0; nf < 7; ++nf)
        acc[mf][nf] = __builtin_amdgcn_mfma_f32_16x16x32_bf16(a[mf], bb[nf], acc[mf][nf], 0, 0, 0);
    if (have) {
      unsigned char* obase = smem + (cbuf ? BBUF0 : BBUF1);
      *(uint4*)(obase + 0*8192 + tid*16) = nx0;
      *(uint4*)(obase + 1*8192 + tid*16) = nx1;
      *(uint4*)(obase + 2*8192 + tid*16) = nx2;
      *(uint4*)(obase + 3*8192 + tid*16) = nx3;
    }
    __syncthreads();
  }

  {
    #pragma unroll
    for (int k = 0; k < 2; ++k) {
      uint4 v = *(const uint4*)(Ap + k*4096 + tid*8);
      *(uint4*)(smem + ABUF0 + k*8192 + tid*16) = v;
    }
  }
  #pragma unroll
  for (int mf = 0; mf < 4; ++mf) {
    #pragma unroll
    for (int nf = 0; nf < 7; ++nf) {
      int colg = (nq*7 + nf)*16 + l15;
      if (colg < 416) {
        #pragma unroll
        for (int i = 0; i < 4; ++i) {
          int row = mh*64 + mf*16 + l4*4 + i;
          float v = fmaxf(acc[mf][nf][i], 0.f);
          *(unsigned short*)(smem + (size_t)((colg >> 3)*128 + row)*16 + (colg & 7)*2) = f2bf(v);
        }
      }
    }
  }
  __syncthreads();

  f32x4 acc2[4][4];
  #pragma unroll
  for (int mf = 0; mf < 4; ++mf)
    #pragma unroll
    for (int nn = 0; nn < 4; ++nn)
      acc2[mf][nn] = (f32x4){0.f,0.f,0.f,0.f};
  const int nf0  = (nq == 0) ? 0 : (1 + 3*nq);
  const int ncnt = (nq == 0) ? 4 : 3;

  for (int s2 = 0; s2 < 13; ++s2) {
    const int cbuf = s2 & 1;
    uint4 nx0, nx1;
    const bool have = (s2 < 12);
    if (have) {
      const __hip_bfloat16* src = Ap + (size_t)(s2+1)*8192;
      nx0 = *(const uint4*)(src + 0*4096 + tid*8);
      nx1 = *(const uint4*)(src + 1*4096 + tid*8);
    }
    bf16x8 a2[4];
    #pragma unroll
    for (int mf = 0; mf < 4; ++mf) {
      int row = mh*64 + mf*16 + l15;
      int fchunk = s2*4 + l4;
      a2[mf] = *(const bf16x8*)(smem + (size_t)(fchunk*128 + row)*16);
    }
    bf16x8 b2[4];
    const unsigned char* bbase = smem + (cbuf ? ABUF1 : ABUF0);
    #pragma unroll
    for (int nn = 0; nn < 4; ++nn) {
      if (nn < ncnt) {
        int col = (nf0 + nn)*16 + l15;
        b2[nn] = *(const bf16x8*)(bbase + (size_t)(l4*256 + col)*16);
      }
    }
    #pragma unroll
    for (int mf = 0; mf < 4; ++mf)
      #pragma unroll
      for (int nn = 0; nn < 4; ++nn)
        if (nn < ncnt)
          acc2[mf][nn] = __builtin_amdgcn_mfma_f32_16x16x32_bf16(a2[mf], b2[nn], acc2[mf][nn], 0, 0, 0);
    if (have) {
      unsigned char* obase = smem + (cbuf ? ABUF0 : ABUF1);
      *(uint4*)(obase + 0*8192 + tid*16) = nx0;
      *(uint4*)(obase + 1*8192 + tid*16) = nx1;
    }
    __syncthreads();
  }

  {
    float abv[4], aqv[4];
    #pragma unroll
    for (int nn = 0; nn < 4; ++nn) {
      int col = (nf0 + nn)*16 + l15;
      bool ok = (nn < ncnt) && (col < Qq);
      abv[nn] = ok ? ab[col] : 0.f;
      aqv[nn] = ok ? aq[col] : 0.f;
    }
    #pragma unroll
    for (int mf = 0; mf < 4; ++mf) {
      #pragma unroll
      for (int i = 0; i < 4; ++i) {
        float p = 0.f;
        #pragma unroll
        for (int nn = 0; nn < 4; ++nn)
          if (nn < ncnt)
            p += tanhf(acc2[mf][nn][i] + abv[nn]) * aqv[nn];
        p += __shfl_xor(p, 1); p += __shfl_xor(p, 2);
        p += __shfl_xor(p, 4); p += __shfl_xor(p, 8);
        if (l15 == 0) atomicAdd(&sscore[mh*64 + mf*16 + l4*4 + i], p);
      }
    }
  }
  __syncthreads();

  if (tid < 4) {
    float mx = -1e30f;
    for (int t = 0; t < Tq; ++t) mx = fmaxf(mx, sscore[tid*32 + t]);
    float sum = 0.f;
    for (int t = 0; t < Tq; ++t) { float e = expf(sscore[tid*32 + t] - mx); sa_[tid*32 + t] = e; sum += e; }
    float inv = 1.f / sum;
    for (int t = 0; t < Tq; ++t) sa_[tid*32 + t] *= inv;
    sa_[tid*32 + 30] = 0.f; sa_[tid*32 + 31] = 0.f;
  }
  __syncthreads();

  {
    const int tt = tid >> 7, fb = tid & 127;
    float rv[4];
    float ls = 0.f, lsq = 0.f;
    #pragma unroll
    for (int q = 0; q < 4; ++q) {
      int f = fb + q*128;
      rv[q] = 0.f;
      if (f < Fq) {
        float r = 0.f;
        const unsigned char* hb = smem + (size_t)(f >> 3)*128*16 + (f & 7)*2;
        for (int t = 0; t < Tq; ++t)
          r += sa_[tt*32 + t] * bf2f(*(const unsigned short*)(hb + (size_t)(tt*32 + t)*16));
        rv[q] = r; ls += r; lsq += r*r;
      }
    }
    #pragma unroll
    for (int off = 32; off >= 1; off >>= 1) { ls += __shfl_xor(ls, off); lsq += __shfl_xor(lsq, off); }
    if (lane == 0) { red_[wid] = ls; red_[8 + wid] = lsq; }
    __syncthreads();
    float tot  = red_[2*tt] + red_[2*tt + 1];
    float totq = red_[8 + 2*tt] + red_[8 + 2*tt + 1];
    float mu = tot * (1.f/Fq);
    float var = totq * (1.f/Fq) - mu*mu;
    float rs = rsqrtf(var + 1e-5f);
    float* dst = (cand ? cand_rep : clicked_rep) + (size_t)(n0 + tt)*Fq;
    #pragma unroll
    for (int q = 0; q < 4; ++q) {
      int f = fb + q*128;
      if (f < Fq) dst[f] = (rv[q] - mu)*rs*lg[f] + lb[f];
    }
  }
}

// ---------------- GI = clicked_rep @ wih^T + bih ----------------
__global__ __launch_bounds__(256) void gi_kernel(
    const float* __restrict__ rep, const float* __restrict__ wih, const float* __restrict__ bih,
    float* __restrict__ gi)
{
  __shared__ __align__(16) float sA[64*80];
  const int tid = threadIdx.x;
  const int rt = blockIdx.x;
  const int g  = blockIdx.y*256 + tid;
  const bool gok = g < G3;
  const float* wr = wih + (size_t)(gok ? g : 0) * Fq;
  float acc[64];
  #pragma unroll
  for (int r = 0; r < 64; ++r) acc[r] = 0.f;
  for (int kt = 0; kt < Fq; kt += 80) {
    __syncthreads();
    for (int i = tid; i < 64*80; i += 256) {
      int r = i / 80, c = i - r*80;
      sA[i] = rep[(size_t)(rt*64 + r)*Fq + kt + c];
    }
    __syncthreads();
    #pragma unroll 2
    for (int k = 0; k < 80; k += 4) {
      float w0 = wr[kt+k], w1 = wr[kt+k+1], w2 = wr[kt+k+2], w3 = wr[kt+k+3];
      #pragma unroll
      for (int r = 0; r < 64; ++r) {
        float4 a4 = *(const float4*)(sA + r*80 + k);
        acc[r] = fmaf(a4.x,w0,fmaf(a4.y,w1,fmaf(a4.z,w2,fmaf(a4.w,w3,acc[r]))));
      }
    }
  }
  if (gok) {
    float bv = bih[g];
    #pragma unroll 1
    for (int r = 0; r < 64; ++r) gi[(size_t)(rt*64+r)*G3 + g] = acc[r] + bv;
  }
}

// ---------------- GRU: 1 block/row, f16 weights streamed from L2, v_dot2 ----------------
__global__ __launch_bounds__(1024) void gru_kernel(
    const float* __restrict__ gi, const _Float16* __restrict__ whhH8,
    const float* __restrict__ bhh, const int* __restrict__ lens,
    float* __restrict__ user_rep)
{
  __shared__ __align__(16) float shf[Fq];        // fp32 carried h
  __shared__ __align__(16) _Float16 sh2[Fq];     // packed f16 copy for matvec
  __shared__ float sgh[G3];
  const int b = blockIdx.x, tid = threadIdx.x;
  const int len = lens[b];
  for (int j = tid; j < Fq; j += 1024) { shf[j] = 0.f; sh2[j] = (_Float16)0.f; }
  __syncthreads();
  const int g2 = tid + 1024;
  const bool g2ok = (g2 < G3);                   // tid < 176
  const uint4* w1 = (const uint4*)whhH8 + tid;   // layout [k8][g][8h] -> uint4 idx k8*G3+g
  const uint4* w2 = (const uint4*)whhH8 + (g2ok ? g2 : tid);
  const float bb1 = bhh[tid];
  const float bb2 = g2ok ? bhh[g2] : 0.f;
  const float* gb = gi + (size_t)b*Hq*G3;

  for (int t = 0; t < len; ++t) {
    float a1 = 0.f, a2 = 0.f;
    const uint4* hp = (const uint4*)sh2;
    #pragma unroll 5
    for (int k8 = 0; k8 < 50; ++k8) {
      uint4 hv = hp[k8];                         // LDS broadcast, 8 halves of h
      uint4 wv = w1[(size_t)k8*G3];              // coalesced 1KB/wave
      a1 = dot8_(hv, wv, a1);
      if (g2ok) {
        uint4 vv = w2[(size_t)k8*G3];
        a2 = dot8_(hv, vv, a2);
      }
    }
    sgh[tid] = a1 + bb1;
    if (g2ok) sgh[g2] = a2 + bb2;
    __syncthreads();
    if (tid < Fq) {
      float r  = sigmoidf_(gb[tid]        + sgh[tid]);
      float z  = sigmoidf_(gb[Fq + tid]   + sgh[Fq + tid]);
      float nn = tanhf   (gb[2*Fq + tid] + r*sgh[2*Fq + tid]);
      float hn = (1.f - z)*nn + z*shf[tid];
      shf[tid] = hn;
      sh2[tid] = (_Float16)hn;
    }
    __syncthreads();
    gb += G3;
  }
  for (int j = tid; j < Fq; j += 1024) user_rep[(size_t)b*Fq + j] = shf[j];
}

__global__ __launch_bounds__(64) void score_kernel(
    const float* __restrict__ cand_rep, const float* __restrict__ user_rep,
    float* __restrict__ out)
{
  const int i = blockIdx.x;
  const int b = i / Sq;
  const int lane = threadIdx.x;
  float acc = 0.f;
  for (int f = lane; f < Fq; f += 64) acc = fmaf(cand_rep[(size_t)i*Fq+f], user_rep[(size_t)b*Fq+f], acc);
  #pragma unroll
  for (int off = 32; off >= 1; off >>= 1) acc += __shfl_xor(acc, off);
  if (lane == 0) out[i] = acc;
}

extern "C" void kernel_launch(void* const* d_in, const int* in_sizes, int n_in,
                              void* d_out, int out_size, void* d_ws, size_t ws_size,
                              hipStream_t stream)
{
  const float* cand_emb = (const float*)d_in[0];
  const float* clk_emb  = (const float*)d_in[1];
  const int*   lens     = (const int*)  d_in[2];
  const float* c_cw = (const float*)d_in[3];
  const float* c_cb = (const float*)d_in[4];
  const float* c_aW = (const float*)d_in[5];
  const float* c_ab = (const float*)d_in[6];
  const float* c_aq = (const float*)d_in[7];
  const float* c_lg = (const float*)d_in[8];
  const float* c_lb = (const float*)d_in[9];
  const float* u_cw = (const float*)d_in[10];
  const float* u_cb = (const float*)d_in[11];
  const float* u_aW = (const float*)d_in[12];
  const float* u_ab = (const float*)d_in[13];
  const float* u_aq = (const float*)d_in[14];
  const float* u_lg = (const float*)d_in[15];
  const float* u_lb = (const float*)d_in[16];
  const float* wih  = (const float*)d_in[17];
  const float* whh  = (const float*)d_in[18];
  const float* bih  = (const float*)d_in[19];
  const float* bhh  = (const float*)d_in[20];

  float* ws = (float*)d_ws;
  float* cand_rep    = ws;                        // 128,000 f
  float* clicked_rep = cand_rep + NCAND*Fq;       // +1,280,000
  float* gi          = clicked_rep + NCLK*Fq;     // +3,840,000
  float* user_rep    = gi + (size_t)NCLK*G3;      // +25,600
  _Float16* whhH8    = (_Float16*)(user_rep + Bq*Fq);  // 480,000 halves
  // bf16 encoder-prep buffers overlay gi (dead until gi_kernel runs)
  __hip_bfloat16* convprep = (__hip_bfloat16*)gi;
  __hip_bfloat16* attprep  = (__hip_bfloat16*)(gi + 491520);

  conv_prep_kernel<<<(2*30*16384 + 255)/256, 256, 0, stream>>>(c_cw, u_cw, convprep);
  att_prep_kernel<<<(2*13*8192 + 255)/256, 256, 0, stream>>>(c_aW, u_aW, attprep);
  whh_h8_prep_kernel<<<(50*G3*8 + 255)/256, 256, 0, stream>>>(whh, whhH8);

  encode_mfma_kernel<<<(NCAND + NCLK)/4, 512, 0, stream>>>(
      cand_emb, clk_emb, convprep, attprep,
      c_cb, c_ab, c_aq, c_lg, c_lb,
      u_cb, u_ab, u_aq, u_lg, u_lb,
      cand_rep, clicked_rep);

  gi_kernel<<<dim3(NCLK/64, 5), 256, 0, stream>>>(clicked_rep, wih, bih, gi);

  gru_kernel<<<Bq, 1024, 0, stream>>>(gi, whhH8, bhh, lens, user_rep);

  score_kernel<<<NCAND, 64, 0, stream>>>(cand_rep, user_rep, (float*)d_out);
}